// Round 5
// baseline (275.424 us; speedup 1.0000x reference)
//
#include <hip/hip_runtime.h>

// ---------------------------------------------------------------------------
// self_transformer: q=xW1^T+b1, k=xW2^T+b2, v=xW3^T+b3,
//                   attn=softmax((k q^T)/sqrt(D)), out=attn@v
// N=4096, D=1024. All matmuls via mfma_f32_16x16x32_bf16, fp32 accum.
// R5: 128x64 tiles everywhere (6-8 blocks/CU for barrier-drain overlap),
//     softmax fused into S-gemm epilogue (E=exp(s), atomic row-sums; divide
//     in final reduce), v^T written directly by projection epilogue.
// ---------------------------------------------------------------------------

typedef short bf16x8 __attribute__((ext_vector_type(8)));  // 8 bf16 = 4 VGPRs
typedef float f32x4  __attribute__((ext_vector_type(4)));

__device__ __forceinline__ short f2bf(float f) {
    unsigned u = __builtin_bit_cast(unsigned, f);
    u += 0x7FFFu + ((u >> 16) & 1u);   // round-to-nearest-even
    return (short)(u >> 16);
}

__device__ __forceinline__ void gld_lds16(const short* g, short* l) {
    __builtin_amdgcn_global_load_lds(
        (const __attribute__((address_space(1))) void*)g,
        (__attribute__((address_space(3))) void*)l, 16, 0, 0);
}

// BT GEMM: C[a][b] = scale * sum_i A[a*lda+i] * B[b*ldb+i]  (+ per-col bias)
// cmode: 0 = bf16 C store; 1 = fp32 C store (split-K partial, z offset);
//        2 = bf16 exp(C) store + atomic fp32 row-sums into rsum.
// If vt!=null and bn0>=vcol0: block writes TRANSPOSED bf16 into
// vt[(col-vcol0)*ldvt + row] instead of C (for v^T production).
// LDS: BK=64, XOR-swizzled 16B granules: LDS granule p of row r holds global
// granule p^(r&7); fragment read granule (ks*4+quad)^(r&7) -> conflict-free.
template<int BM, int BN>
__global__ __launch_bounds__(256)
void gemm_bt(const short* __restrict__ A, int lda,
             const short* __restrict__ B, int ldb,
             const float* __restrict__ bias,
             void* __restrict__ Cout, int ldc, int cmode, float scale,
             int K, size_t zstride,
             float* __restrict__ rsum,
             short* __restrict__ vt, int vcol0, int ldvt)
{
    constexpr int NT = BN / 32;                 // MFMA col-tiles per wave
    __shared__ __align__(16) short As[BM * 64];
    __shared__ __align__(16) short Bs[BN * 64];

    const int tid  = threadIdx.x;
    const int lane = tid & 63;
    const int wave = tid >> 6;
    const int wm   = (wave >> 1) * 64;          // wave row offset
    const int wn   = (wave & 1) * (BN / 2);     // wave col offset
    const int quad = lane >> 4;
    const int l16  = lane & 15;
    const size_t bm0 = (size_t)blockIdx.y * BM;
    const size_t bn0 = (size_t)blockIdx.x * BN;
    const int koff = blockIdx.z * K;

    f32x4 acc[4][NT] = {};

    // staging lane decode: chunk row + swizzled global granule
    const int srow = lane >> 3;                        // 0..7
    const int scol = ((lane & 7) ^ srow) << 3;         // swizzled elem col
    const short* Ag = A + (bm0 + srow) * (size_t)lda + koff + scol;
    const short* Bg = B + (bn0 + srow) * (size_t)ldb + koff + scol;

    for (int k0 = 0; k0 < K; k0 += 64) {
#pragma unroll
        for (int cc = 0; cc < BM / 8; cc += 4) {
            const int c = cc + wave;
            gld_lds16(Ag + (size_t)c * 8 * lda + k0, &As[c * 512]);
        }
#pragma unroll
        for (int cc = 0; cc < BN / 8; cc += 4) {
            const int c = cc + wave;
            gld_lds16(Bg + (size_t)c * 8 * ldb + k0, &Bs[c * 512]);
        }
        __syncthreads();

#pragma unroll
        for (int ks = 0; ks < 2; ks++) {
            const int sw = (ks << 2) + quad;
            bf16x8 af[4], bfr[NT];
#pragma unroll
            for (int mt = 0; mt < 4; mt++) {
                const int r = wm + mt * 16 + l16;
                af[mt] = *(const bf16x8*)(&As[r * 64 + ((sw ^ (r & 7)) << 3)]);
            }
#pragma unroll
            for (int nt = 0; nt < NT; nt++) {
                const int r = wn + nt * 16 + l16;
                bfr[nt] = *(const bf16x8*)(&Bs[r * 64 + ((sw ^ (r & 7)) << 3)]);
            }
#pragma unroll
            for (int mt = 0; mt < 4; mt++)
#pragma unroll
                for (int nt = 0; nt < NT; nt++)
                    acc[mt][nt] = __builtin_amdgcn_mfma_f32_16x16x32_bf16(
                        af[mt], bfr[nt], acc[mt][nt], 0, 0, 0);
        }
        __syncthreads();
    }

    // epilogue: C/D layout col=lane&15, row=quad*4+reg
    const bool dotrans = (vt != nullptr) && (bn0 >= (size_t)vcol0);
    float* Cf = (float*)Cout + blockIdx.z * zstride;
    short* Cs = (short*)Cout;
    float rp[4][4];
#pragma unroll
    for (int mt = 0; mt < 4; mt++)
#pragma unroll
        for (int r = 0; r < 4; r++) rp[mt][r] = 0.0f;

#pragma unroll
    for (int mt = 0; mt < 4; mt++) {
#pragma unroll
        for (int nt = 0; nt < NT; nt++) {
            const size_t col = bn0 + wn + nt * 16 + l16;
            const float bc = bias ? bias[col] : 0.0f;
            if (dotrans) {
                short4 o;
#pragma unroll
                for (int r = 0; r < 4; r++)
                    ((short*)&o)[r] = f2bf(acc[mt][nt][r] * scale + bc);
                const size_t row0 = bm0 + wm + mt * 16 + quad * 4;
                *(short4*)(vt + (col - vcol0) * (size_t)ldvt + row0) = o;
            } else if (cmode == 1) {
#pragma unroll
                for (int r = 0; r < 4; r++) {
                    const size_t row = bm0 + wm + mt * 16 + quad * 4 + r;
                    Cf[row * (size_t)ldc + col] = acc[mt][nt][r] * scale + bc;
                }
            } else if (cmode == 2) {
#pragma unroll
                for (int r = 0; r < 4; r++) {
                    const size_t row = bm0 + wm + mt * 16 + quad * 4 + r;
                    const float e = __expf(acc[mt][nt][r] * scale + bc);
                    Cs[row * (size_t)ldc + col] = f2bf(e);
                    rp[mt][r] += e;
                }
            } else {
#pragma unroll
                for (int r = 0; r < 4; r++) {
                    const size_t row = bm0 + wm + mt * 16 + quad * 4 + r;
                    Cs[row * (size_t)ldc + col] = f2bf(acc[mt][nt][r] * scale + bc);
                }
            }
        }
    }

    if (cmode == 2) {
        // reduce each rp over the 16 l16 lanes within the quad, one atomic per row
#pragma unroll
        for (int mt = 0; mt < 4; mt++)
#pragma unroll
            for (int r = 0; r < 4; r++) {
                float s = rp[mt][r];
                s += __shfl_xor(s, 1);
                s += __shfl_xor(s, 2);
                s += __shfl_xor(s, 4);
                s += __shfl_xor(s, 8);
                if (l16 == 0)
                    atomicAdd(&rsum[bm0 + wm + mt * 16 + quad * 4 + r], s);
            }
    }
}

__global__ __launch_bounds__(256)
void zerofill(float* __restrict__ p, int n)
{
    const int i = blockIdx.x * 256 + threadIdx.x;
    if (i < n) p[i] = 0.0f;
}

// out[i4] = (p0+p1) * (1/rsum[row]);  1024 fp32 per row -> row = i4>>8
__global__ __launch_bounds__(256)
void reduce2div(const float* __restrict__ p, const float* __restrict__ rsum,
                float* __restrict__ out, int n4)
{
    const int i = blockIdx.x * 256 + threadIdx.x;
    if (i >= n4) return;
    const float4 a = ((const float4*)p)[i];
    const float4 b = ((const float4*)(p + (size_t)4096 * 1024))[i];
    const float inv = 1.0f / rsum[i >> 8];
    float4 o;
    o.x = (a.x + b.x) * inv; o.y = (a.y + b.y) * inv;
    o.z = (a.z + b.z) * inv; o.w = (a.w + b.w) * inv;
    ((float4*)out)[i] = o;
}

__global__ __launch_bounds__(256)
void cast4(const float* __restrict__ in, short* __restrict__ out, int n4)
{
    const int i = blockIdx.x * 256 + threadIdx.x;
    if (i >= n4) return;
    const float4 f = ((const float4*)in)[i];
    short4 o;
    o.x = f2bf(f.x); o.y = f2bf(f.y); o.z = f2bf(f.z); o.w = f2bf(f.w);
    ((short4*)out)[i] = o;
}

__global__ __launch_bounds__(256)
void cast_w3(const float* __restrict__ W1, const float* __restrict__ W2,
             const float* __restrict__ W3, short* __restrict__ out, int per4)
{
    const int i = blockIdx.x * 256 + threadIdx.x;
    if (i >= 3 * per4) return;
    const float* src = (i < per4) ? W1 : (i < 2 * per4 ? W2 : W3);
    const int j = (i < per4) ? i : (i < 2 * per4 ? i - per4 : i - 2 * per4);
    const float4 f = ((const float4*)src)[j];
    short4 o;
    o.x = f2bf(f.x); o.y = f2bf(f.y); o.z = f2bf(f.z); o.w = f2bf(f.w);
    ((short4*)out)[i] = o;
}

__global__ __launch_bounds__(256)
void bias_cat3(const float* __restrict__ b1, const float* __restrict__ b2,
               const float* __restrict__ b3, float* __restrict__ cat, int n)
{
    const int i = blockIdx.x * 256 + threadIdx.x;
    if (i < n) cat[i] = b1[i];
    else if (i < 2 * n) cat[i] = b2[i - n];
    else if (i < 3 * n) cat[i] = b3[i - 2 * n];
}

extern "C" void kernel_launch(void* const* d_in, const int* in_sizes, int n_in,
                              void* d_out, int out_size, void* d_ws, size_t ws_size,
                              hipStream_t stream)
{
    const float* x  = (const float*)d_in[0];
    const float* W1 = (const float*)d_in[1];
    const float* b1 = (const float*)d_in[2];
    const float* W2 = (const float*)d_in[3];
    const float* b2 = (const float*)d_in[4];
    const float* W3 = (const float*)d_in[5];
    const float* b3 = (const float*)d_in[6];
    float* out = (float*)d_out;

    const int N = 4096, D = 1024;

    // workspace layout (peak ~72 MB):
    //   vt   [0, 8M)              live: qkv-gemm .. out-gemm
    //   E    [8M, 40M)            live: S-gemm .. out-gemm
    //   rsum [40M, +16K)          live: S-gemm .. reduce
    //   xb/Wb/bcat/qk at [40.02M, ~70.1M)  -- all dead after S-gemm
    //   outp [40.02M, 72.02M)     overlays the dead region (out-gemm..reduce)
    char* wsb = (char*)d_ws;
    short* vt   = (short*)wsb;                           // 1024 x 4096 bf16
    short* E    = (short*)(wsb + (size_t)8 * 1024 * 1024);   // 4096 x 4096 bf16
    float* rsum = (float*)(wsb + (size_t)40 * 1024 * 1024);  // 4096 fp32
    char* dead  = wsb + (size_t)40 * 1024 * 1024 + 16384;
    short* xb   = (short*)dead;                          // 4096 x 1024 bf16
    short* Wb   = xb + (size_t)N * D;                    // 3072 x 1024 bf16
    float* bcat = (float*)(Wb + (size_t)3 * D * D);      // 3072 fp32
    short* qk   = (short*)(bcat + 3 * D);                // 4096 x 2048 bf16
    float* outp = (float*)dead;                          // 2 x 4096 x 1024 fp32

    // 0) zero row-sum accumulators
    zerofill<<<16, 256, 0, stream>>>(rsum, N);

    // 1) casts
    cast4<<<(N * D / 4) / 256, 256, 0, stream>>>(x, xb, N * D / 4);
    cast_w3<<<(3 * D * D / 4) / 256, 256, 0, stream>>>(W1, W2, W3, Wb, D * D / 4);
    bias_cat3<<<(3 * D + 255) / 256, 256, 0, stream>>>(b1, b2, b3, bcat, D);

    // 2) qkv = x @ [W1;W2;W3]^T + bias; q,k -> qk[4096x2048], v -> vt^T
    //    grid (48,32)=1536 blocks (6/CU)
    dim3 gqkv(3 * D / 64, N / 128);
    gemm_bt<128, 64><<<gqkv, 256, 0, stream>>>(xb, D, Wb, D, bcat,
                                               qk, 2 * D, 0, 1.0f, D, 0,
                                               nullptr, vt, 2 * D, N);

    // 3) E = exp((k q^T)/32) bf16 + atomic row-sums; grid (64,32)=2048 (8/CU)
    dim3 gs(N / 64, N / 128);
    gemm_bt<128, 64><<<gs, 256, 0, stream>>>(qk + D, 2 * D, qk, 2 * D, nullptr,
                                             E, N, 2, 0.03125f, D, 0,
                                             rsum, nullptr, 0, 0);

    // 4) out partials = E @ vt^T, split-K=2; grid (16,32,2)=1024 blocks
    dim3 go(D / 64, N / 128, 2);
    gemm_bt<128, 64><<<go, 256, 0, stream>>>(E, N, vt, N, nullptr,
                                             outp, D, 1, 1.0f, N / 2,
                                             (size_t)N * D, nullptr,
                                             nullptr, 0, 0);

    // 5) out = (p0 + p1) / rowsum
    reduce2div<<<(N * D / 4) / 256, 256, 0, stream>>>(outp, rsum, out, N * D / 4);
}

// Round 7
// 245.423 us; speedup vs baseline: 1.1222x; 1.1222x over previous
//
#include <hip/hip_runtime.h>

// ---------------------------------------------------------------------------
// self_transformer: q=xW1^T+b1, k=xW2^T+b2, v=xW3^T+b3,
//                   attn=softmax((k q^T)/sqrt(D)), out=attn@v
// N=4096, D=1024. All matmuls via mfma_f32_16x16x32_bf16, fp32 accum.
// R7 = R6 with the prep-kernel W2/W3 offset bug fixed (element offsets
//     1048576/2097152, not byte offsets): qkv 128x96 grid 1024, E-gemm
//     128x128 grid 1024 (exp fused, no atomics), out 128x128 split-K=4
//     bf16 partials, fused rowsum+reduce+divide.
// ---------------------------------------------------------------------------

typedef short bf16x8 __attribute__((ext_vector_type(8)));  // 8 bf16 = 4 VGPRs
typedef float f32x4  __attribute__((ext_vector_type(4)));

__device__ __forceinline__ short f2bf(float f) {
    unsigned u = __builtin_bit_cast(unsigned, f);
    u += 0x7FFFu + ((u >> 16) & 1u);   // round-to-nearest-even
    return (short)(u >> 16);
}
__device__ __forceinline__ float bf2f(short s) {
    return __builtin_bit_cast(float, (unsigned)((unsigned short)s) << 16);
}

__device__ __forceinline__ void gld_lds16(const short* g, short* l) {
    __builtin_amdgcn_global_load_lds(
        (const __attribute__((address_space(1))) void*)g,
        (__attribute__((address_space(3))) void*)l, 16, 0, 0);
}

// BT GEMM: C[a][b] = scale * sum_i A[a*lda+i] * B[b*ldb+i]  (+ per-col bias)
// cmode: 0 = bf16 store; 2 = bf16 exp() store; 3 = bf16 store at split-K
//        offset z*zstride (A/B k-offset z*K).
// LDS: BK=64, XOR-swizzled 16B granules: LDS granule p of row r holds global
// granule p^(r&7); fragment read granule (ks*4+quad)^(r&7) -> conflict-free.
template<int BM, int BN>
__global__ __launch_bounds__(256)
void gemm_bt(const short* __restrict__ A, int lda,
             const short* __restrict__ B, int ldb,
             const float* __restrict__ bias,
             short* __restrict__ Cout, int ldc, int cmode, float scale,
             int K, size_t zstride)
{
    constexpr int NT = BN / 32;                 // MFMA col-tiles per wave
    __shared__ __align__(16) short As[BM * 64];
    __shared__ __align__(16) short Bs[BN * 64];

    const int tid  = threadIdx.x;
    const int lane = tid & 63;
    const int wave = tid >> 6;
    const int wm   = (wave >> 1) * 64;          // wave row offset
    const int wn   = (wave & 1) * (BN / 2);     // wave col offset
    const int quad = lane >> 4;
    const int l16  = lane & 15;
    const size_t bm0 = (size_t)blockIdx.y * BM;
    const size_t bn0 = (size_t)blockIdx.x * BN;
    const int koff = blockIdx.z * K;

    f32x4 acc[4][NT] = {};

    // staging lane decode: chunk row + swizzled global granule
    const int srow = lane >> 3;                        // 0..7
    const int scol = ((lane & 7) ^ srow) << 3;         // swizzled elem col
    const short* Ag = A + (bm0 + srow) * (size_t)lda + koff + scol;
    const short* Bg = B + (bn0 + srow) * (size_t)ldb + koff + scol;

    for (int k0 = 0; k0 < K; k0 += 64) {
#pragma unroll
        for (int cc = 0; cc < BM / 8; cc += 4) {
            const int c = cc + wave;
            gld_lds16(Ag + (size_t)c * 8 * lda + k0, &As[c * 512]);
        }
#pragma unroll
        for (int cc = 0; cc < BN / 8; cc += 4) {
            const int c = cc + wave;
            gld_lds16(Bg + (size_t)c * 8 * ldb + k0, &Bs[c * 512]);
        }
        __syncthreads();

#pragma unroll
        for (int ks = 0; ks < 2; ks++) {
            const int sw = (ks << 2) + quad;
            bf16x8 af[4], bfr[NT];
#pragma unroll
            for (int mt = 0; mt < 4; mt++) {
                const int r = wm + mt * 16 + l16;
                af[mt] = *(const bf16x8*)(&As[r * 64 + ((sw ^ (r & 7)) << 3)]);
            }
#pragma unroll
            for (int nt = 0; nt < NT; nt++) {
                const int r = wn + nt * 16 + l16;
                bfr[nt] = *(const bf16x8*)(&Bs[r * 64 + ((sw ^ (r & 7)) << 3)]);
            }
#pragma unroll
            for (int mt = 0; mt < 4; mt++)
#pragma unroll
                for (int nt = 0; nt < NT; nt++)
                    acc[mt][nt] = __builtin_amdgcn_mfma_f32_16x16x32_bf16(
                        af[mt], bfr[nt], acc[mt][nt], 0, 0, 0);
        }
        __syncthreads();
    }

    // epilogue: C/D layout col=lane&15, row=quad*4+reg
    short* Cs = Cout + ((cmode == 3) ? blockIdx.z * zstride : 0);
#pragma unroll
    for (int mt = 0; mt < 4; mt++) {
#pragma unroll
        for (int nt = 0; nt < NT; nt++) {
            const size_t col = bn0 + wn + nt * 16 + l16;
            const float bc = bias ? bias[col] : 0.0f;
#pragma unroll
            for (int r = 0; r < 4; r++) {
                const size_t row = bm0 + wm + mt * 16 + quad * 4 + r;
                float v = acc[mt][nt][r] * scale + bc;
                if (cmode == 2) v = __expf(v);
                Cs[row * (size_t)ldc + col] = f2bf(v);
            }
        }
    }
}

// 64x64 LDS-tiled transpose: vt[d][n] = qkv[n*3072 + 2048 + d]
__global__ __launch_bounds__(256)
void transpose_v(const short* __restrict__ qkv, short* __restrict__ vt)
{
    __shared__ short sh[64][72];   // +8 pad
    const int n0 = blockIdx.x * 64, d0 = blockIdx.y * 64;
    const int t = threadIdx.x;
    const int r = t >> 2, c = (t & 3) << 4;

    const short* src = qkv + (size_t)(n0 + r) * 3072 + 2048 + d0 + c;
    *(int4*)(&sh[r][c])     = *(const int4*)(src);
    *(int4*)(&sh[r][c + 8]) = *(const int4*)(src + 8);
    __syncthreads();

    short tmp[16];
#pragma unroll
    for (int j = 0; j < 16; j++) tmp[j] = sh[c + j][r];
    short* dst = vt + (size_t)(d0 + r) * 4096 + n0 + c;
    *(int4*)(dst)     = *(const int4*)(tmp);
    *(int4*)(dst + 8) = *(const int4*)(tmp + 8);
}

// One block per output row n: rsum = sum(E[n,:]); out[n,:] =
// (sum_z partial_z[n,:]) / rsum. Partials are bf16, 4 splits of 4096x1024.
__global__ __launch_bounds__(256)
void reduce4div(const short* __restrict__ E, const short* __restrict__ outp,
                float* __restrict__ out)
{
    const int row = blockIdx.x;
    const int t = threadIdx.x;
    const int wave = t >> 6, lane = t & 63;

    // row-sum of E[row][4096], 16 elems/thread
    const short* e = E + (size_t)row * 4096 + (t << 4);
    short sh[16];
    *(int4*)(sh)     = *(const int4*)(e);
    *(int4*)(sh + 8) = *(const int4*)(e + 8);
    float s = 0.0f;
#pragma unroll
    for (int i = 0; i < 16; i++) s += bf2f(sh[i]);
#pragma unroll
    for (int off = 32; off; off >>= 1) s += __shfl_down(s, off);
    __shared__ float red[4];
    if (lane == 0) red[wave] = s;
    __syncthreads();
    const float inv = 1.0f / (red[0] + red[1] + red[2] + red[3]);

    // sum 4 bf16 partial rows, 4 cols/thread
    const size_t base = (size_t)row * 1024 + (t << 2);
    float a[4] = {0.0f, 0.0f, 0.0f, 0.0f};
#pragma unroll
    for (int z = 0; z < 4; z++) {
        short4 p = *(const short4*)(outp + z * (size_t)4096 * 1024 + base);
        a[0] += bf2f(p.x); a[1] += bf2f(p.y);
        a[2] += bf2f(p.z); a[3] += bf2f(p.w);
    }
    float4 o;
    o.x = a[0] * inv; o.y = a[1] * inv; o.z = a[2] * inv; o.w = a[3] * inv;
    *(float4*)(out + base) = o;
}

// single prep: x->xb (1M float4), W1|W2|W3 -> Wb (3x256K float4), bias cat
// NOTE: Wb sub-matrix offsets are in SHORT ELEMENTS: each W is 1024*1024 =
// 1048576 elements (R6 bug: used byte offsets 2097152/4194304 -> k,v garbage).
__global__ __launch_bounds__(256)
void prep(const float* __restrict__ x, const float* __restrict__ W1,
          const float* __restrict__ W2, const float* __restrict__ W3,
          const float* __restrict__ b1, const float* __restrict__ b2,
          const float* __restrict__ b3,
          short* __restrict__ xb, short* __restrict__ Wb,
          float* __restrict__ bcat)
{
    const int i = blockIdx.x * 256 + threadIdx.x;
    const int NX = 1048576;           // 4096*1024/4
    const int NW = 262144;            // 1024*1024/4
    if (i < NX + 3 * NW) {
        const float* src; short* dst; int j;
        if (i < NX)               { src = x;  dst = xb; j = i; }
        else if (i < NX + NW)     { src = W1; dst = Wb; j = i - NX; }
        else if (i < NX + 2 * NW) { src = W2; dst = Wb + 1048576; j = i - NX - NW; }
        else                      { src = W3; dst = Wb + 2097152; j = i - NX - 2 * NW; }
        const float4 f = ((const float4*)src)[j];
        short4 o;
        o.x = f2bf(f.x); o.y = f2bf(f.y); o.z = f2bf(f.z); o.w = f2bf(f.w);
        *(short4*)(dst + (j << 2)) = o;
    } else {
        const int j = i - (NX + 3 * NW);
        if (j < 3072)
            bcat[j] = (j < 1024) ? b1[j] : (j < 2048 ? b2[j - 1024] : b3[j - 2048]);
    }
}

extern "C" void kernel_launch(void* const* d_in, const int* in_sizes, int n_in,
                              void* d_out, int out_size, void* d_ws, size_t ws_size,
                              hipStream_t stream)
{
    const float* x  = (const float*)d_in[0];
    const float* W1 = (const float*)d_in[1];
    const float* b1 = (const float*)d_in[2];
    const float* W2 = (const float*)d_in[3];
    const float* b2 = (const float*)d_in[4];
    const float* W3 = (const float*)d_in[5];
    const float* b3 = (const float*)d_in[6];
    float* out = (float*)d_out;

    const int N = 4096, D = 1024;

    // workspace (peak 79 MB):
    //   vt   [0, 8M)            live: transpose .. out-gemm
    //   E    [8M, 40M)          live: S-gemm .. reduce
    //   xb   [40M, 48M)  \
    //   Wb   [48M, 54M)   }     dead after S-gemm
    //   bcat [54M, +12K)  }
    //   qkv  [54M+16K, ~78M)   /
    //   outp [40M, 72M)         bf16 partials, overlays dead region
    char* wsb = (char*)d_ws;
    short* vt   = (short*)wsb;                               // 1024x4096 bf16
    short* E    = (short*)(wsb + (size_t)8  * 1024 * 1024);  // 4096x4096 bf16
    short* xb   = (short*)(wsb + (size_t)40 * 1024 * 1024);  // 4096x1024 bf16
    short* Wb   = (short*)(wsb + (size_t)48 * 1024 * 1024);  // 3072x1024 bf16
    float* bcat = (float*)(wsb + (size_t)54 * 1024 * 1024);  // 3072 fp32
    short* qkv  = (short*)(wsb + (size_t)54 * 1024 * 1024 + 16384); // 4096x3072
    short* outp = (short*)(wsb + (size_t)40 * 1024 * 1024);  // 4x 4096x1024 bf16

    // 1) prep: casts + bias concat (one launch)
    prep<<<(1048576 + 3 * 262144 + 3072 + 255) / 256, 256, 0, stream>>>(
        x, W1, W2, W3, b1, b2, b3, xb, Wb, bcat);

    // 2) qkv = x @ [W1;W2;W3]^T + bias  (128x96, grid (32,32)=1024, 4/CU)
    dim3 gqkv(3 * D / 96, N / 128);
    gemm_bt<128, 96><<<gqkv, 256, 0, stream>>>(xb, D, Wb, D, bcat,
                                               qkv, 3 * D, 0, 1.0f, D, 0);

    // 3) vt[d][n] = v[n][d]   grid (64,16)=1024 blocks
    dim3 gt(N / 64, D / 64);
    transpose_v<<<gt, 256, 0, stream>>>(qkv, vt);

    // 4) E = exp((k q^T)/32) bf16  (128x128, grid (32,32)=1024, 4/CU)
    dim3 gs(N / 128, N / 128);
    gemm_bt<128, 128><<<gs, 256, 0, stream>>>(qkv + D, 3 * D, qkv, 3 * D,
                                              nullptr, E, N, 2, 0.03125f, D, 0);

    // 5) out partials = E @ vt^T, split-K=4, bf16 (grid (8,32,4)=1024)
    dim3 go(D / 128, N / 128, 4);
    gemm_bt<128, 128><<<go, 256, 0, stream>>>(E, N, vt, N, nullptr,
                                              outp, D, 3, 1.0f, N / 4,
                                              (size_t)N * D);

    // 6) out = (sum_z partial_z) / rowsum(E)
    reduce4div<<<N, 256, 0, stream>>>(E, outp, out);
}